// Round 10
// baseline (128.322 us; speedup 1.0000x reference)
//
#include <hip/hip_runtime.h>
#include <math.h>

// DigitCaps dynamic routing, MI355X. Round 17: revert to R13/R14 champion
// (62.0us main) + two strictly-local instruction cuts in the routing loops.
//
// R16 post-mortem: prefetch+fusion regressed (73.1us); compiler sank the
// prefetched loads back to use sites (VGPR fell to 44) and the fused accp
// chain worsened scheduling. Invariant held a 7th time: VALUBusy*dur=47.5us.
//
// Session model: VALU busy volume pinned at ~46-48us across 7 structures;
// best dur 62.0us at 77% busy. Only winning move class: instruction/latency
// cuts in the hot path with geometry FIXED (R12 DPP, R13 b128+4buf).
//
// Round 17 (champion + 2 local cuts, geometry untouched):
//  1. exp2-domain logits: Vp packs V*log2e, e = exp2f(br) -> deletes the
//     v_mul inside all 28 exp calls/wave, shortens each br->e chain by one
//     step. Same-magnitude fp16 V rounding as before (V was already fp16).
//  2. mask-free Z: pad routes (k=13, lane>=32) have uh==0 -> br=0 ->
//     e=1.0 EXACTLY; drop the cndmask and subtract the exact 32.0 from the
//     wave-summed Z instead.
//
// Carried structure (R12+R13+R14): prepacked fp16 W chunks [op4][rl128][p2],
// global_load_lds width=16 linear-dest, 4 LDS buffers / 4 barriers
// {S0S1S2|S3C0C1|S4S5C2C3|S6C4C5|C6}, paired-o ds_read_b128, DPP wave
// reductions into SGPRs, fp16 uh cache, XCD-bijective swizzle, 896-padded
// routes (no guards in u_hat).

#define BB 128
#define JJ 166
#define RR 864
#define OO 8
#define KMAX 14            // 14 k-slots of 64 routes; k=13 lanes>=32 are pad
#define WP_U2 (JJ * 7168)  // W fp16: per j: 7 chunks * 1024 uint2 = 57,344 B
#define UP_U2 (BB * 896)   // u fp16: [b][896] uint2, routes >=864 zeroed
#define LOG2E 1.4426950408889634f

typedef __fp16 h2v __attribute__((ext_vector_type(2)));

static __device__ __forceinline__ uint32_t pack2(float a, float b) {
    return __builtin_bit_cast(uint32_t, __builtin_amdgcn_cvt_pkrtz(a, b));
}
static __device__ __forceinline__ h2v bc_h2(uint32_t u) {
    return __builtin_bit_cast(h2v, u);
}
static __device__ __forceinline__ float lo_f(uint32_t u) {
    return (float)__builtin_bit_cast(h2v, u).x;
}
static __device__ __forceinline__ float hi_f(uint32_t u) {
    return (float)__builtin_bit_cast(h2v, u).y;
}

// Full-wave (64-lane) sum via DPP cascade; total lands in lane 63, then
// readlane -> SGPR (uniform across the wave). All-lanes-active required.
static __device__ __forceinline__ float dpp_wave_sum(float x) {
#define DPP_STEP(CTRL)                                                         \
    x += __builtin_bit_cast(                                                   \
        float, __builtin_amdgcn_update_dpp(0, __builtin_bit_cast(int, x),      \
                                           (CTRL), 0xF, 0xF, true));
    DPP_STEP(0x111)  // row_shr:1
    DPP_STEP(0x112)  // row_shr:2
    DPP_STEP(0x114)  // row_shr:4
    DPP_STEP(0x118)  // row_shr:8  -> lane15/31/47/63 hold row sums
    DPP_STEP(0x142)  // row_bcast:15 -> lane31 = sum(0..31), lane63 = sum(32..63)
    DPP_STEP(0x143)  // row_bcast:31 -> lane63 = total
#undef DPP_STEP
    return __builtin_bit_cast(
        float, __builtin_amdgcn_readlane(__builtin_bit_cast(int, x), 63));
}

// ---- pre-pass: W -> fp16 Wp[j][c7][op4][rl128][p2]; u -> fp16 uT[b][896] ----
__global__ __launch_bounds__(256) void prepack_kernel(
    const float* __restrict__ u, const float* __restrict__ W,
    uint2* __restrict__ ws) {
    const int t = threadIdx.x;
    const int bid = blockIdx.x;
    if (bid < JJ * 7) {
        const int j = bid / 7;
        const int c = bid - j * 7;
        const float4* __restrict__ W4 = (const float4*)W;  // [(j*864+r)*8+o]
        uint2* __restrict__ dst = ws + (size_t)bid * 1024;
#pragma unroll
        for (int i = 0; i < 4; ++i) {
            const int e = i * 256 + t;   // e = op*256 + rl*2 + p
            const int op = e >> 8;
            const int rl = (e & 255) >> 1;
            const int p = e & 1;
            const int o = 2 * op + p;
            const int r = c * 128 + rl;
            float4 w = make_float4(0.f, 0.f, 0.f, 0.f);
            if (r < RR) w = W4[((size_t)j * RR + r) * 8 + o];
            dst[e] = make_uint2(pack2(w.x, w.y), pack2(w.z, w.w));
        }
    } else {
        // u pack: e in [0, 128*896)
        const int e = (bid - JJ * 7) * 256 + t;
        const int b = e / 896;
        const int r = e - b * 896;
        const float4* __restrict__ u4 = (const float4*)u;
        float4 uu = make_float4(0.f, 0.f, 0.f, 0.f);
        if (r < RR) uu = u4[(size_t)b * RR + r];
        ws[WP_U2 + e] = make_uint2(pack2(uu.x, uu.y), pack2(uu.z, uu.w));
    }
}

__global__ __launch_bounds__(256, 4) void digitcaps_kernel(
    const uint2* __restrict__ Wp, const uint2* __restrict__ uP,
    float* __restrict__ out) {
    const int tid = threadIdx.x;
    const int lane = tid & 63;
    const int wave = tid >> 6;

    // XCD-bijective swizzle: 5312 blocks = 8 XCDs x 664. The 32 same-j
    // blocks become consecutive on one XCD -> Wp[j] (56 KB) L2-hot.
    int bid = blockIdx.x;
    bid = (bid & 7) * 664 + (bid >> 3);
    const int j = bid >> 5;
    const int b = ((bid & 31) << 2) + wave;

    // four W buffers, each one 128-route chunk [op][rl][p] uint2: 32,768 B
    __shared__ uint2 wlds[4][1024];

    const uint2* __restrict__ uPb = uP + (size_t)b * 896;

    uint32_t uh[KMAX][4];  // u_hat packed fp16 pairs; constant-indexed only

    // ---- stage chunk CC into LDS buffer BUF via async global->LDS ----
#define STAGE(CC, BUF)                                                         \
    {                                                                          \
        const char* gsrc = (const char*)(Wp + ((size_t)j * 7 + (CC)) * 1024);  \
        _Pragma("unroll")                                                      \
        for (int i = 0; i < 2; ++i) {                                          \
            __builtin_amdgcn_global_load_lds(                                  \
                (const __attribute__((address_space(1))) uint32_t*)            \
                    (gsrc + i * 4096 + tid * 16),                              \
                (__attribute__((address_space(3))) uint32_t*)                  \
                    ((char*)(&wlds[BUF][0]) + i * 4096 + (wave << 10)),        \
                16, 0, 0);                                                     \
        }                                                                      \
    }

    // ---- u_hat for chunk CC: 2 k-slots, 4 x ds_read_b128 per slot ----
#define COMPUTE(CC, BUF)                                                       \
    {                                                                          \
        _Pragma("unroll")                                                      \
        for (int kl = 0; kl < 2; ++kl) {                                       \
            const int rl = (kl << 6) + lane;                                   \
            const uint2 up = uPb[(CC) * 128 + rl];                             \
            _Pragma("unroll")                                                  \
            for (int op = 0; op < 4; ++op) {                                   \
                const uint4 ww =                                               \
                    *(const uint4*)(&wlds[BUF][op * 256 + (rl << 1)]);         \
                float t0 = __builtin_amdgcn_fdot2(bc_h2(ww.x), bc_h2(up.x),    \
                                                  0.0f, false);                \
                const float d0 = __builtin_amdgcn_fdot2(bc_h2(ww.y),           \
                                                        bc_h2(up.y), t0,      \
                                                        false);               \
                float t1 = __builtin_amdgcn_fdot2(bc_h2(ww.z), bc_h2(up.x),    \
                                                  0.0f, false);                \
                const float d1 = __builtin_amdgcn_fdot2(bc_h2(ww.w),           \
                                                        bc_h2(up.y), t1,      \
                                                        false);               \
                uh[(CC) * 2 + kl][op] = pack2(d0, d1);                         \
            }                                                                  \
        }                                                                      \
    }

    // 4-buffer schedule; each buffer's re-stage barrier-separated from its
    // last read: {S0 S1 S2 | S3 C0 C1 | S4 S5 C2 C3 | S6 C4 C5 | C6}
    STAGE(0, 0) STAGE(1, 1) STAGE(2, 2)
    __syncthreads();
    STAGE(3, 3) COMPUTE(0, 0) COMPUTE(1, 1)
    __syncthreads();
    STAGE(4, 0) STAGE(5, 1) COMPUTE(2, 2) COMPUTE(3, 3)
    __syncthreads();
    STAGE(6, 2) COMPUTE(4, 0) COMPUTE(5, 1)
    __syncthreads();
    COMPUTE(6, 2)
#undef STAGE
#undef COMPUTE

    float V[OO];  // running sum of past v's (b_r = <uhat_r, V>)
    float v[OO];

    // ---- iteration 0: b=0 -> c uniform = 1/R (packed fp16 partial sums) ----
    {
        h2v accp[4];
#pragma unroll
        for (int o2 = 0; o2 < 4; ++o2) accp[o2] = bc_h2(uh[0][o2]);
#pragma unroll
        for (int k = 1; k < KMAX; ++k)
#pragma unroll
            for (int o2 = 0; o2 < 4; ++o2) accp[o2] += bc_h2(uh[k][o2]);

        float s[OO];
#pragma unroll
        for (int o2 = 0; o2 < 4; ++o2) {
            s[2 * o2]     = dpp_wave_sum((float)accp[o2].x) * (1.0f / (float)RR);
            s[2 * o2 + 1] = dpp_wave_sum((float)accp[o2].y) * (1.0f / (float)RR);
        }
        float n2 = 0.0f;
#pragma unroll
        for (int o = 0; o < OO; ++o) n2 += s[o] * s[o];
        const float scale = sqrtf(n2) / (1.0f + n2);
#pragma unroll
        for (int o = 0; o < OO; ++o) { v[o] = s[o] * scale; V[o] = v[o]; }
    }

    // ---- iterations 1 and 2 ----
#pragma unroll
    for (int it = 1; it < 3; ++it) {
        // pack V*log2e once per iteration: br lands in log2 domain, so the
        // exp is a bare v_exp_f32 (no per-k v_mul).
        uint32_t Vp[4];
#pragma unroll
        for (int o2 = 0; o2 < 4; ++o2)
            Vp[o2] = pack2(V[2 * o2] * LOG2E, V[2 * o2 + 1] * LOG2E);

        float zp = 0.0f;
        float sp[OO];
#pragma unroll
        for (int o = 0; o < OO; ++o) sp[o] = 0.0f;

#pragma unroll
        for (int k = 0; k < KMAX; ++k) {
            float br = 0.0f;
#pragma unroll
            for (int o2 = 0; o2 < 4; ++o2)
                br = __builtin_amdgcn_fdot2(bc_h2(uh[k][o2]), bc_h2(Vp[o2]),
                                            br, false);
            // no pad mask: pad routes (k=13, lane>=32) have uh==0 -> br=0
            // -> e=1.0 exactly; the exact +32.0 Z pollution is subtracted
            // after the wave sum. sp is unaffected (e*0 contributions).
            const float e = exp2f(br);
            zp += e;
#pragma unroll
            for (int o2 = 0; o2 < 4; ++o2) {
                sp[2 * o2]     = fmaf(e, lo_f(uh[k][o2]), sp[2 * o2]);
                sp[2 * o2 + 1] = fmaf(e, hi_f(uh[k][o2]), sp[2 * o2 + 1]);
            }
        }
        const float invZ = 1.0f / (dpp_wave_sum(zp) - 32.0f);

        float s[OO];
#pragma unroll
        for (int o = 0; o < OO; ++o) s[o] = dpp_wave_sum(sp[o]) * invZ;

        float n2 = 0.0f;
#pragma unroll
        for (int o = 0; o < OO; ++o) n2 += s[o] * s[o];
        const float scale = sqrtf(n2) / (1.0f + n2);
#pragma unroll
        for (int o = 0; o < OO; ++o) v[o] = s[o] * scale;

        if (it < 2) {
#pragma unroll
            for (int o = 0; o < OO; ++o) V[o] += v[o];
        }
    }

    // ---- write out[b][j][o]; v uniform across lanes (SGPR sums) ----
    float outv = 0.0f;
#pragma unroll
    for (int o = 0; o < OO; ++o)
        if (lane == o) outv = v[o];
    if (lane < OO) out[(b * JJ + j) * OO + lane] = outv;
}

extern "C" void kernel_launch(void* const* d_in, const int* in_sizes, int n_in,
                              void* d_out, int out_size, void* d_ws, size_t ws_size,
                              hipStream_t stream) {
    const float* u = (const float*)d_in[0];  // [128, 864, 4]
    const float* W = (const float*)d_in[1];  // [1, 166, 864, 8, 4]
    float* out = (float*)d_out;              // [128, 166, 8]
    uint2* ws = (uint2*)d_ws;                // needs (WP_U2 + UP_U2)*8 ~= 10.3 MB

    // pre-pass: 166*7 W-chunk blocks + 448 u blocks
    prepack_kernel<<<JJ * 7 + (BB * 896) / 256, 256, 0, stream>>>(u, W, ws);

    // main: 166 j * 32 b-groups, 256 threads = 4 waves = 4 b's
    digitcaps_kernel<<<JJ * 32, 256, 0, stream>>>(ws, ws + WP_U2, out);
}

// Round 11
// 123.077 us; speedup vs baseline: 1.0426x; 1.0426x over previous
//
#include <hip/hip_runtime.h>
#include <math.h>

// DigitCaps dynamic routing, MI355X. Round 18: exact revert to the R13/R14
// champion (62.0us main, 123.4us bench) — the session's best.
//
// R17 post-mortem: exp2f regressed (62.0 -> 66.2us; VALUBusy*dur rose to
// ~51us from the pinned 47.5) — exp2f lowers to OCML __ocml_exp2_f32 with
// range-handling guards, while __expf is the native v_mul+v_exp_f32 path.
// The "cut" added volume. Maskless-Z likely neutral. Lesson: __expf was
// already optimal; OCML non-native entry points are not free.
//
// Session model (8 structures, R7-R17): VALU busy volume pinned at
// ~46-48us; this champion achieves 62.0us at 76.5% VALUBusy — the best
// utilization measured. All geometric neighbors benched and lost:
// 2-wave split +38%, lane=batch +58%, VMEM-W +150%, 512-thr +15%,
// prefetch/fusion +18%, exp2/maskless +7%. Noise band (±3-5%) exceeds any
// credible remaining local gain.
//
// Structure: prepacked fp16 W chunks [op4][rl128][p2] (swizzle-the-source),
// global_load_lds width=16 linear-dest staging, 4 LDS buffers / 4 barriers
// {S0S1S2|S3C0C1|S4S5C2C3|S6C4C5|C6}, paired-o ds_read_b128, fp16 uh
// register cache, DPP wave reductions into SGPRs, __expf softmax with pad
// masking, XCD-bijective swizzle, 896-padded routes (no guards in u_hat).

#define BB 128
#define JJ 166
#define RR 864
#define OO 8
#define KMAX 14            // 14 k-slots of 64 routes; k=13 lanes>=32 are pad
#define WP_U2 (JJ * 7168)  // W fp16: per j: 7 chunks * 1024 uint2 = 57,344 B
#define UP_U2 (BB * 896)   // u fp16: [b][896] uint2, routes >=864 zeroed

typedef __fp16 h2v __attribute__((ext_vector_type(2)));

static __device__ __forceinline__ uint32_t pack2(float a, float b) {
    return __builtin_bit_cast(uint32_t, __builtin_amdgcn_cvt_pkrtz(a, b));
}
static __device__ __forceinline__ h2v bc_h2(uint32_t u) {
    return __builtin_bit_cast(h2v, u);
}
static __device__ __forceinline__ float lo_f(uint32_t u) {
    return (float)__builtin_bit_cast(h2v, u).x;
}
static __device__ __forceinline__ float hi_f(uint32_t u) {
    return (float)__builtin_bit_cast(h2v, u).y;
}

// Full-wave (64-lane) sum via DPP cascade; total lands in lane 63, then
// readlane -> SGPR (uniform across the wave). All-lanes-active required.
static __device__ __forceinline__ float dpp_wave_sum(float x) {
#define DPP_STEP(CTRL)                                                         \
    x += __builtin_bit_cast(                                                   \
        float, __builtin_amdgcn_update_dpp(0, __builtin_bit_cast(int, x),      \
                                           (CTRL), 0xF, 0xF, true));
    DPP_STEP(0x111)  // row_shr:1
    DPP_STEP(0x112)  // row_shr:2
    DPP_STEP(0x114)  // row_shr:4
    DPP_STEP(0x118)  // row_shr:8  -> lane15/31/47/63 hold row sums
    DPP_STEP(0x142)  // row_bcast:15 -> lane31 = sum(0..31), lane63 = sum(32..63)
    DPP_STEP(0x143)  // row_bcast:31 -> lane63 = total
#undef DPP_STEP
    return __builtin_bit_cast(
        float, __builtin_amdgcn_readlane(__builtin_bit_cast(int, x), 63));
}

// ---- pre-pass: W -> fp16 Wp[j][c7][op4][rl128][p2]; u -> fp16 uT[b][896] ----
__global__ __launch_bounds__(256) void prepack_kernel(
    const float* __restrict__ u, const float* __restrict__ W,
    uint2* __restrict__ ws) {
    const int t = threadIdx.x;
    const int bid = blockIdx.x;
    if (bid < JJ * 7) {
        const int j = bid / 7;
        const int c = bid - j * 7;
        const float4* __restrict__ W4 = (const float4*)W;  // [(j*864+r)*8+o]
        uint2* __restrict__ dst = ws + (size_t)bid * 1024;
#pragma unroll
        for (int i = 0; i < 4; ++i) {
            const int e = i * 256 + t;   // e = op*256 + rl*2 + p
            const int op = e >> 8;
            const int rl = (e & 255) >> 1;
            const int p = e & 1;
            const int o = 2 * op + p;
            const int r = c * 128 + rl;
            float4 w = make_float4(0.f, 0.f, 0.f, 0.f);
            if (r < RR) w = W4[((size_t)j * RR + r) * 8 + o];
            dst[e] = make_uint2(pack2(w.x, w.y), pack2(w.z, w.w));
        }
    } else {
        // u pack: e in [0, 128*896)
        const int e = (bid - JJ * 7) * 256 + t;
        const int b = e / 896;
        const int r = e - b * 896;
        const float4* __restrict__ u4 = (const float4*)u;
        float4 uu = make_float4(0.f, 0.f, 0.f, 0.f);
        if (r < RR) uu = u4[(size_t)b * RR + r];
        ws[WP_U2 + e] = make_uint2(pack2(uu.x, uu.y), pack2(uu.z, uu.w));
    }
}

__global__ __launch_bounds__(256, 4) void digitcaps_kernel(
    const uint2* __restrict__ Wp, const uint2* __restrict__ uP,
    float* __restrict__ out) {
    const int tid = threadIdx.x;
    const int lane = tid & 63;
    const int wave = tid >> 6;

    // XCD-bijective swizzle: 5312 blocks = 8 XCDs x 664. The 32 same-j
    // blocks become consecutive on one XCD -> Wp[j] (56 KB) L2-hot.
    int bid = blockIdx.x;
    bid = (bid & 7) * 664 + (bid >> 3);
    const int j = bid >> 5;
    const int b = ((bid & 31) << 2) + wave;

    // four W buffers, each one 128-route chunk [op][rl][p] uint2: 32,768 B
    __shared__ uint2 wlds[4][1024];

    const uint2* __restrict__ uPb = uP + (size_t)b * 896;

    uint32_t uh[KMAX][4];  // u_hat packed fp16 pairs; constant-indexed only

    // ---- stage chunk CC into LDS buffer BUF via async global->LDS ----
#define STAGE(CC, BUF)                                                         \
    {                                                                          \
        const char* gsrc = (const char*)(Wp + ((size_t)j * 7 + (CC)) * 1024);  \
        _Pragma("unroll")                                                      \
        for (int i = 0; i < 2; ++i) {                                          \
            __builtin_amdgcn_global_load_lds(                                  \
                (const __attribute__((address_space(1))) uint32_t*)            \
                    (gsrc + i * 4096 + tid * 16),                              \
                (__attribute__((address_space(3))) uint32_t*)                  \
                    ((char*)(&wlds[BUF][0]) + i * 4096 + (wave << 10)),        \
                16, 0, 0);                                                     \
        }                                                                      \
    }

    // ---- u_hat for chunk CC: 2 k-slots, 4 x ds_read_b128 per slot ----
#define COMPUTE(CC, BUF)                                                       \
    {                                                                          \
        _Pragma("unroll")                                                      \
        for (int kl = 0; kl < 2; ++kl) {                                       \
            const int rl = (kl << 6) + lane;                                   \
            const uint2 up = uPb[(CC) * 128 + rl];                             \
            _Pragma("unroll")                                                  \
            for (int op = 0; op < 4; ++op) {                                   \
                const uint4 ww =                                               \
                    *(const uint4*)(&wlds[BUF][op * 256 + (rl << 1)]);         \
                float t0 = __builtin_amdgcn_fdot2(bc_h2(ww.x), bc_h2(up.x),    \
                                                  0.0f, false);                \
                const float d0 = __builtin_amdgcn_fdot2(bc_h2(ww.y),           \
                                                        bc_h2(up.y), t0,      \
                                                        false);               \
                float t1 = __builtin_amdgcn_fdot2(bc_h2(ww.z), bc_h2(up.x),    \
                                                  0.0f, false);                \
                const float d1 = __builtin_amdgcn_fdot2(bc_h2(ww.w),           \
                                                        bc_h2(up.y), t1,      \
                                                        false);               \
                uh[(CC) * 2 + kl][op] = pack2(d0, d1);                         \
            }                                                                  \
        }                                                                      \
    }

    // 4-buffer schedule; each buffer's re-stage barrier-separated from its
    // last read: {S0 S1 S2 | S3 C0 C1 | S4 S5 C2 C3 | S6 C4 C5 | C6}
    STAGE(0, 0) STAGE(1, 1) STAGE(2, 2)
    __syncthreads();
    STAGE(3, 3) COMPUTE(0, 0) COMPUTE(1, 1)
    __syncthreads();
    STAGE(4, 0) STAGE(5, 1) COMPUTE(2, 2) COMPUTE(3, 3)
    __syncthreads();
    STAGE(6, 2) COMPUTE(4, 0) COMPUTE(5, 1)
    __syncthreads();
    COMPUTE(6, 2)
#undef STAGE
#undef COMPUTE

    float V[OO];  // running sum of past v's (b_r = <uhat_r, V>)
    float v[OO];

    // ---- iteration 0: b=0 -> c uniform = 1/R (packed fp16 partial sums) ----
    {
        h2v accp[4];
#pragma unroll
        for (int o2 = 0; o2 < 4; ++o2) accp[o2] = bc_h2(uh[0][o2]);
#pragma unroll
        for (int k = 1; k < KMAX; ++k)
#pragma unroll
            for (int o2 = 0; o2 < 4; ++o2) accp[o2] += bc_h2(uh[k][o2]);

        float s[OO];
#pragma unroll
        for (int o2 = 0; o2 < 4; ++o2) {
            s[2 * o2]     = dpp_wave_sum((float)accp[o2].x) * (1.0f / (float)RR);
            s[2 * o2 + 1] = dpp_wave_sum((float)accp[o2].y) * (1.0f / (float)RR);
        }
        float n2 = 0.0f;
#pragma unroll
        for (int o = 0; o < OO; ++o) n2 += s[o] * s[o];
        const float scale = sqrtf(n2) / (1.0f + n2);
#pragma unroll
        for (int o = 0; o < OO; ++o) { v[o] = s[o] * scale; V[o] = v[o]; }
    }

    // ---- iterations 1 and 2 ----
#pragma unroll
    for (int it = 1; it < 3; ++it) {
        // pack V once per iteration for dot2 logits
        uint32_t Vp[4];
#pragma unroll
        for (int o2 = 0; o2 < 4; ++o2)
            Vp[o2] = pack2(V[2 * o2], V[2 * o2 + 1]);

        float zp = 0.0f;
        float sp[OO];
#pragma unroll
        for (int o = 0; o < OO; ++o) sp[o] = 0.0f;

#pragma unroll
        for (int k = 0; k < KMAX; ++k) {
            float br = 0.0f;
#pragma unroll
            for (int o2 = 0; o2 < 4; ++o2)
                br = __builtin_amdgcn_fdot2(bc_h2(uh[k][o2]), bc_h2(Vp[o2]),
                                            br, false);
            // mask pad routes (k==13, lane>=32): exp(0)=1 would pollute Z
            const float e = (k < KMAX - 1 || lane < 32) ? __expf(br) : 0.0f;
            zp += e;
#pragma unroll
            for (int o2 = 0; o2 < 4; ++o2) {
                sp[2 * o2]     = fmaf(e, lo_f(uh[k][o2]), sp[2 * o2]);
                sp[2 * o2 + 1] = fmaf(e, hi_f(uh[k][o2]), sp[2 * o2 + 1]);
            }
        }
        const float invZ = 1.0f / dpp_wave_sum(zp);

        float s[OO];
#pragma unroll
        for (int o = 0; o < OO; ++o) s[o] = dpp_wave_sum(sp[o]) * invZ;

        float n2 = 0.0f;
#pragma unroll
        for (int o = 0; o < OO; ++o) n2 += s[o] * s[o];
        const float scale = sqrtf(n2) / (1.0f + n2);
#pragma unroll
        for (int o = 0; o < OO; ++o) v[o] = s[o] * scale;

        if (it < 2) {
#pragma unroll
            for (int o = 0; o < OO; ++o) V[o] += v[o];
        }
    }

    // ---- write out[b][j][o]; v uniform across lanes (SGPR sums) ----
    float outv = 0.0f;
#pragma unroll
    for (int o = 0; o < OO; ++o)
        if (lane == o) outv = v[o];
    if (lane < OO) out[(b * JJ + j) * OO + lane] = outv;
}

extern "C" void kernel_launch(void* const* d_in, const int* in_sizes, int n_in,
                              void* d_out, int out_size, void* d_ws, size_t ws_size,
                              hipStream_t stream) {
    const float* u = (const float*)d_in[0];  // [128, 864, 4]
    const float* W = (const float*)d_in[1];  // [1, 166, 864, 8, 4]
    float* out = (float*)d_out;              // [128, 166, 8]
    uint2* ws = (uint2*)d_ws;                // needs (WP_U2 + UP_U2)*8 ~= 10.3 MB

    // pre-pass: 166*7 W-chunk blocks + 448 u blocks
    prepack_kernel<<<JJ * 7 + (BB * 896) / 256, 256, 0, stream>>>(u, W, ws);

    // main: 166 j * 32 b-groups, 256 threads = 4 waves = 4 b's
    digitcaps_kernel<<<JJ * 32, 256, 0, stream>>>(ws, ws + WP_U2, out);
}